// Round 8
// baseline (41.569 us; speedup 1.0000x reference)
//
#include <hip/hip_runtime.h>

// QuantumAttention: out[b,s,e] = sum_q q[b,s,q] * W_dec[e,q] + x[b,s,e]
//   angles = x @ W_enc^T, c = cos(angles)
//   q[0] = prod(c[1..7]); q[i] = prod(c[0..i])
//
// R8: two-kernel split. K1 computes qv[tok][8] (R7 structure minus decode;
// 0.5 MB write to d_ws). K2 is a pure stream: read qv (block-uniform) + x
// (L3-hot from K1) -> decode + residual -> nontemporal store. No reduction
// behind any memory latency in K2; K1 has no heavy epilogue. Fallback to
// fused kernel if ws_size < 512 KB.

typedef float v2f __attribute__((ext_vector_type(2)));
typedef float v4f __attribute__((ext_vector_type(4)));

#define EDIM 1024
#define QDIM 8
#define NTOK 16384
#define BLOCK 256
#define T 4
#define GRID1 (NTOK / T)     // 4096
#define TK2 8
#define GRID2 (NTOK / TK2)   // 2048

template<int CTRL>
__device__ __forceinline__ float dpp_add(float v) {
    int m = __builtin_amdgcn_update_dpp(0, __float_as_int(v), CTRL, 0xF, 0xF, true);
    return v + __int_as_float(m);
}

// 64-lane sum on the VALU pipe; result valid in lane 63 only.
__device__ __forceinline__ float wave_sum63(float v) {
    v = dpp_add<0x111>(v);   // row_shr:1
    v = dpp_add<0x112>(v);   // row_shr:2
    v = dpp_add<0x114>(v);   // row_shr:4
    v = dpp_add<0x118>(v);   // row_shr:8
    v = dpp_add<0x142>(v);   // row_bcast:15
    v = dpp_add<0x143>(v);   // row_bcast:31
    return v;
}

// ---------------- K1: angles -> qv (d_ws) ----------------
__global__ __launch_bounds__(BLOCK, 2)
void qattn_angles(const float* __restrict__ x,
                  const float* __restrict__ W_enc,   // [Q][E]
                  float* __restrict__ qbuf)          // [NTOK][QDIM]
{
    __shared__ float red[T][4][QDIM];

    const int t    = threadIdx.x;
    const int lane = t & 63;
    const int wave = t >> 6;
    const int e0   = t * 4;
    const int tok0 = blockIdx.x * T;

    v4f xv[T];
#pragma unroll
    for (int i = 0; i < T; ++i)
        xv[i] = *(const v4f*)(x + (size_t)(tok0 + i) * EDIM + e0);

    v4f wenc[QDIM];
#pragma unroll
    for (int q = 0; q < QDIM; ++q)
        wenc[q] = *(const v4f*)(W_enc + q * EDIM + e0);

    float ang[T][QDIM];
#pragma unroll
    for (int i = 0; i < T; ++i) {
        v2f x01 = (v2f){xv[i].x, xv[i].y};
        v2f x23 = (v2f){xv[i].z, xv[i].w};
#pragma unroll
        for (int q = 0; q < QDIM; ++q) {
            v2f acc = x01 * (v2f){wenc[q].x, wenc[q].y};
            acc = __builtin_elementwise_fma(x23, (v2f){wenc[q].z, wenc[q].w}, acc);
            ang[i][q] = acc.x + acc.y;
        }
    }

#pragma unroll
    for (int i = 0; i < T; ++i)
#pragma unroll
        for (int q = 0; q < QDIM; ++q)
            ang[i][q] = wave_sum63(ang[i][q]);

    if (lane == 63) {
#pragma unroll
        for (int i = 0; i < T; ++i) {
            *(v4f*)&red[i][wave][0] = (v4f){ang[i][0], ang[i][1], ang[i][2], ang[i][3]};
            *(v4f*)&red[i][wave][4] = (v4f){ang[i][4], ang[i][5], ang[i][6], ang[i][7]};
        }
    }
    __syncthreads();

    // threads 0..T-1: finish token t (sum 4 wave partials, cos, cumprod, store)
    if (t < T) {
        v4f slo = (v4f){0.f, 0.f, 0.f, 0.f};
        v4f shi = (v4f){0.f, 0.f, 0.f, 0.f};
#pragma unroll
        for (int w = 0; w < 4; ++w) {
            slo += *(const v4f*)&red[t][w][0];
            shi += *(const v4f*)&red[t][w][4];
        }
        float c[QDIM];
        c[0] = __cosf(slo.x); c[1] = __cosf(slo.y);
        c[2] = __cosf(slo.z); c[3] = __cosf(slo.w);
        c[4] = __cosf(shi.x); c[5] = __cosf(shi.y);
        c[6] = __cosf(shi.z); c[7] = __cosf(shi.w);

        float qv[QDIM];
        float q0 = c[1];
#pragma unroll
        for (int q = 2; q < QDIM; ++q) q0 *= c[q];
        qv[0] = q0;
        float p = c[0];
#pragma unroll
        for (int q = 1; q < QDIM; ++q) { p *= c[q]; qv[q] = p; }

        float* dst = qbuf + (size_t)(tok0 + t) * QDIM;
        *(v4f*)(dst)     = (v4f){qv[0], qv[1], qv[2], qv[3]};
        *(v4f*)(dst + 4) = (v4f){qv[4], qv[5], qv[6], qv[7]};
    }
}

// ---------------- K2: decode + residual (pure stream) ----------------
__global__ __launch_bounds__(BLOCK, 2)
void qattn_decode(const float* __restrict__ x,
                  const float* __restrict__ W_dec,   // [E][Q]
                  const float* __restrict__ qbuf,    // [NTOK][QDIM]
                  float* __restrict__ out)
{
    const int t  = threadIdx.x;
    const int e0 = t * 4;
    const int tok0 = blockIdx.x * TK2;

    v4f wdlo[4], wdhi[4];
#pragma unroll
    for (int j = 0; j < 4; ++j) {
        wdlo[j] = *(const v4f*)(W_dec + (e0 + j) * QDIM);
        wdhi[j] = *(const v4f*)(W_dec + (e0 + j) * QDIM + 4);
    }

#pragma unroll
    for (int i = 0; i < TK2; ++i) {
        const size_t tok = (size_t)(tok0 + i);
        v4f qlo = *(const v4f*)(qbuf + tok * QDIM);      // block-uniform
        v4f qhi = *(const v4f*)(qbuf + tok * QDIM + 4);
        v4f xv  = *(const v4f*)(x + tok * EDIM + e0);

        float oacc[4];
#pragma unroll
        for (int j = 0; j < 4; ++j) {
            v4f a = qlo * wdlo[j];
            a = __builtin_elementwise_fma(qhi, wdhi[j], a);
            v2f h = (v2f){a.x, a.y} + (v2f){a.z, a.w};
            oacc[j] = h.x + h.y;
        }
        v4f o = xv + (v4f){oacc[0], oacc[1], oacc[2], oacc[3]};
        __builtin_nontemporal_store(o, (v4f*)(out + tok * EDIM + e0));
    }
}

// ---------------- fallback: fused (R7 structure) ----------------
__global__ __launch_bounds__(BLOCK, 2)
void qattn_fused(const float* __restrict__ x,
                 const float* __restrict__ W_enc,
                 const float* __restrict__ W_dec,
                 float* __restrict__ out)
{
    __shared__ float red[T][4][QDIM];

    const int t    = threadIdx.x;
    const int lane = t & 63;
    const int wave = t >> 6;
    const int e0   = t * 4;
    const int tok0 = blockIdx.x * T;

    v4f xv[T];
#pragma unroll
    for (int i = 0; i < T; ++i)
        xv[i] = *(const v4f*)(x + (size_t)(tok0 + i) * EDIM + e0);

    v4f wenc[QDIM];
#pragma unroll
    for (int q = 0; q < QDIM; ++q)
        wenc[q] = *(const v4f*)(W_enc + q * EDIM + e0);

    v4f wdlo[4], wdhi[4];
#pragma unroll
    for (int j = 0; j < 4; ++j) {
        wdlo[j] = *(const v4f*)(W_dec + (e0 + j) * QDIM);
        wdhi[j] = *(const v4f*)(W_dec + (e0 + j) * QDIM + 4);
    }

    float ang[T][QDIM];
#pragma unroll
    for (int i = 0; i < T; ++i) {
        v2f x01 = (v2f){xv[i].x, xv[i].y};
        v2f x23 = (v2f){xv[i].z, xv[i].w};
#pragma unroll
        for (int q = 0; q < QDIM; ++q) {
            v2f acc = x01 * (v2f){wenc[q].x, wenc[q].y};
            acc = __builtin_elementwise_fma(x23, (v2f){wenc[q].z, wenc[q].w}, acc);
            ang[i][q] = acc.x + acc.y;
        }
    }

#pragma unroll
    for (int i = 0; i < T; ++i)
#pragma unroll
        for (int q = 0; q < QDIM; ++q)
            ang[i][q] = wave_sum63(ang[i][q]);

    if (lane == 63) {
#pragma unroll
        for (int i = 0; i < T; ++i) {
            *(v4f*)&red[i][wave][0] = (v4f){ang[i][0], ang[i][1], ang[i][2], ang[i][3]};
            *(v4f*)&red[i][wave][4] = (v4f){ang[i][4], ang[i][5], ang[i][6], ang[i][7]};
        }
    }
    __syncthreads();

#pragma unroll
    for (int i = 0; i < T; ++i) {
        v4f slo = (v4f){0.f, 0.f, 0.f, 0.f};
        v4f shi = (v4f){0.f, 0.f, 0.f, 0.f};
#pragma unroll
        for (int w = 0; w < 4; ++w) {
            slo += *(const v4f*)&red[i][w][0];
            shi += *(const v4f*)&red[i][w][4];
        }
        float c[QDIM];
        c[0] = __cosf(slo.x); c[1] = __cosf(slo.y);
        c[2] = __cosf(slo.z); c[3] = __cosf(slo.w);
        c[4] = __cosf(shi.x); c[5] = __cosf(shi.y);
        c[6] = __cosf(shi.z); c[7] = __cosf(shi.w);

        float qv[QDIM];
        float q0 = c[1];
#pragma unroll
        for (int q = 2; q < QDIM; ++q) q0 *= c[q];
        qv[0] = q0;
        float p = c[0];
#pragma unroll
        for (int q = 1; q < QDIM; ++q) { p *= c[q]; qv[q] = p; }

        v4f qlo = (v4f){qv[0], qv[1], qv[2], qv[3]};
        v4f qhi = (v4f){qv[4], qv[5], qv[6], qv[7]};

        float oacc[4];
#pragma unroll
        for (int j = 0; j < 4; ++j) {
            v4f a = qlo * wdlo[j];
            a = __builtin_elementwise_fma(qhi, wdhi[j], a);
            v2f h = (v2f){a.x, a.y} + (v2f){a.z, a.w};
            oacc[j] = h.x + h.y;
        }
        v4f o = xv[i] + (v4f){oacc[0], oacc[1], oacc[2], oacc[3]};
        __builtin_nontemporal_store(o, (v4f*)(out + (size_t)(tok0 + i) * EDIM + e0));
    }
}

extern "C" void kernel_launch(void* const* d_in, const int* in_sizes, int n_in,
                              void* d_out, int out_size, void* d_ws, size_t ws_size,
                              hipStream_t stream) {
    const float* x     = (const float*)d_in[0];
    const float* W_enc = (const float*)d_in[1];
    const float* W_dec = (const float*)d_in[2];
    float* out         = (float*)d_out;

    const size_t need = (size_t)NTOK * QDIM * sizeof(float);   // 512 KB
    if (ws_size >= need) {
        float* qbuf = (float*)d_ws;
        hipLaunchKernelGGL(qattn_angles, dim3(GRID1), dim3(BLOCK), 0, stream,
                           x, W_enc, qbuf);
        hipLaunchKernelGGL(qattn_decode, dim3(GRID2), dim3(BLOCK), 0, stream,
                           x, W_dec, qbuf, out);
    } else {
        hipLaunchKernelGGL(qattn_fused, dim3(GRID1), dim3(BLOCK), 0, stream,
                           x, W_enc, W_dec, out);
    }
}

// Round 9
// 30.674 us; speedup vs baseline: 1.3552x; 1.3552x over previous
//
#include <hip/hip_runtime.h>

// QuantumAttention: out[b,s,e] = sum_q q[b,s,q] * W_dec[e,q] + x[b,s,e]
//   angles = x @ W_enc^T, c = cos(angles)
//   q[0] = prod(c[1..7]); q[i] = prod(c[0..i])
//
// R9: deduplicated combine. The fused kernels made all 256 threads re-read
// 4 wave-partials per token (8 broadcast ds_read_b128 each) and redo
// cos/cumprod -> ~2k LDS instr/CU = 8-10us of per-CU LDS pipe. Now:
//  P1: all waves encode + 6-stage DPP reduce, lane63 publishes partials.
//  P2: wave 0 alone: sum 4 partials, cos, cumprod via 3-stage DPP
//      multiply-scan in 8-lane groups (2 scans; q0 without division).
//  P3: decode reads just 2 broadcast b128 of qv per token per wave.
// 8 tokens/block loaded up front (128B/lane in flight), grid 2048.

typedef float v2f __attribute__((ext_vector_type(2)));
typedef float v4f __attribute__((ext_vector_type(4)));

#define EDIM 1024
#define QDIM 8
#define NTOK 16384
#define BLOCK 256
#define T 8
#define GRID (NTOK / T)   // 2048

// v += dpp_move(v); bound_ctrl=true -> out-of-range lanes contribute 0
template<int CTRL>
__device__ __forceinline__ float dpp_add(float v) {
    int m = __builtin_amdgcn_update_dpp(0, __float_as_int(v), CTRL, 0xF, 0xF, true);
    return v + __int_as_float(m);
}

// 64-lane sum on the VALU pipe; result valid in lane 63 only.
__device__ __forceinline__ float wave_sum63(float v) {
    v = dpp_add<0x111>(v);   // row_shr:1
    v = dpp_add<0x112>(v);   // row_shr:2
    v = dpp_add<0x114>(v);   // row_shr:4
    v = dpp_add<0x118>(v);   // row_shr:8
    v = dpp_add<0x142>(v);   // row_bcast:15
    v = dpp_add<0x143>(v);   // row_bcast:31
    return v;
}

// one Hillis-Steele step of an inclusive product-scan within 8-lane groups:
// p *= (laneq >= K ? value from lane-K : 1.0)
template<int K>
__device__ __forceinline__ float scan_mul_step(float p, int laneq) {
    int m = __builtin_amdgcn_update_dpp(0, __float_as_int(p), 0x110 | K, 0xF, 0xF, true);
    float tmul = (laneq >= K) ? __int_as_float(m) : 1.0f;
    return p * tmul;
}

__global__ __launch_bounds__(BLOCK, 2)
void qattn_kernel(const float* __restrict__ x,
                  const float* __restrict__ W_enc,   // [Q][E]
                  const float* __restrict__ W_dec,   // [E][Q]
                  float* __restrict__ out)
{
    __shared__ float red[T][4][QDIM];   // wave partials, 1 KB
    __shared__ float qv_s[T][QDIM];     // final q-values, 256 B

    const int t    = threadIdx.x;
    const int lane = t & 63;
    const int wave = t >> 6;
    const int e0   = t * 4;
    const int tok0 = blockIdx.x * T;

    // ---- all 8 tokens' x up front: 8 independent coalesced loads ----
    v4f xv[T];
#pragma unroll
    for (int i = 0; i < T; ++i)
        xv[i] = *(const v4f*)(x + (size_t)(tok0 + i) * EDIM + e0);

    v4f wenc[QDIM];
#pragma unroll
    for (int q = 0; q < QDIM; ++q)
        wenc[q] = *(const v4f*)(W_enc + q * EDIM + e0);

    // ---- phase 1: encode + DPP reduce, in 2 half-groups (caps live regs) ----
#pragma unroll
    for (int h = 0; h < 2; ++h) {
        float ang[4][QDIM];
#pragma unroll
        for (int i = 0; i < 4; ++i) {
            const int ii = h * 4 + i;
            v2f x01 = (v2f){xv[ii].x, xv[ii].y};
            v2f x23 = (v2f){xv[ii].z, xv[ii].w};
#pragma unroll
            for (int q = 0; q < QDIM; ++q) {
                v2f acc = x01 * (v2f){wenc[q].x, wenc[q].y};
                acc = __builtin_elementwise_fma(x23, (v2f){wenc[q].z, wenc[q].w}, acc);
                ang[i][q] = acc.x + acc.y;
            }
        }
#pragma unroll
        for (int i = 0; i < 4; ++i)
#pragma unroll
            for (int q = 0; q < QDIM; ++q)
                ang[i][q] = wave_sum63(ang[i][q]);

        if (lane == 63) {
#pragma unroll
            for (int i = 0; i < 4; ++i) {
                *(v4f*)&red[h * 4 + i][wave][0] =
                    (v4f){ang[i][0], ang[i][1], ang[i][2], ang[i][3]};
                *(v4f*)&red[h * 4 + i][wave][4] =
                    (v4f){ang[i][4], ang[i][5], ang[i][6], ang[i][7]};
            }
        }
    }
    __syncthreads();

    // ---- phase 2: wave 0 finishes all 8 tokens (lane = tok*8 + q) ----
    if (wave == 0) {
        const int tk = lane >> 3;
        const int q  = lane & 7;
        float s = red[tk][0][q] + red[tk][1][q] + red[tk][2][q] + red[tk][3][q];
        float c = __cosf(s);

        // inclusive prefix product: lane q -> c0*...*cq  (= qv[q] for q>=1)
        float p = c;
        p = scan_mul_step<1>(p, q);
        p = scan_mul_step<2>(p, q);
        p = scan_mul_step<4>(p, q);

        // q0 = c1*...*c7: same scan with c0 replaced by 1 (no division)
        float b = (q == 0) ? 1.0f : c;
        b = scan_mul_step<1>(b, q);
        b = scan_mul_step<2>(b, q);
        b = scan_mul_step<4>(b, q);

        if (q > 0)  qv_s[tk][q] = p;
        if (q == 7) qv_s[tk][0] = b;
    }
    __syncthreads();

    // ---- phase 3: decode + residual (2 broadcast b128 qv reads per token) ----
    v4f wdlo[4], wdhi[4];
#pragma unroll
    for (int j = 0; j < 4; ++j) {
        wdlo[j] = *(const v4f*)(W_dec + (e0 + j) * QDIM);
        wdhi[j] = *(const v4f*)(W_dec + (e0 + j) * QDIM + 4);
    }
#pragma unroll
    for (int i = 0; i < T; ++i) {
        v4f qlo = *(const v4f*)&qv_s[i][0];
        v4f qhi = *(const v4f*)&qv_s[i][4];
        float oacc[4];
#pragma unroll
        for (int j = 0; j < 4; ++j) {
            v4f a = qlo * wdlo[j];
            a = __builtin_elementwise_fma(qhi, wdhi[j], a);
            v2f hh = (v2f){a.x, a.y} + (v2f){a.z, a.w};
            oacc[j] = hh.x + hh.y;
        }
        v4f o = xv[i] + (v4f){oacc[0], oacc[1], oacc[2], oacc[3]};
        __builtin_nontemporal_store(o, (v4f*)(out + (size_t)(tok0 + i) * EDIM + e0));
    }
}

extern "C" void kernel_launch(void* const* d_in, const int* in_sizes, int n_in,
                              void* d_out, int out_size, void* d_ws, size_t ws_size,
                              hipStream_t stream) {
    const float* x     = (const float*)d_in[0];
    const float* W_enc = (const float*)d_in[1];
    const float* W_dec = (const float*)d_in[2];
    float* out         = (float*)d_out;

    hipLaunchKernelGGL(qattn_kernel, dim3(GRID), dim3(BLOCK), 0, stream,
                       x, W_enc, W_dec, out);
}